// Round 1
// baseline (361.379 us; speedup 1.0000x reference)
//
#include <hip/hip_runtime.h>

using f32x4  = __attribute__((ext_vector_type(4))) float;
using bf16x8 = __attribute__((ext_vector_type(8))) __bf16;

static constexpr int DD = 512;
static constexpr int D2 = 1024;
static constexpr int NTOK = 4096;  // B*V

__device__ __forceinline__ float bf2f(unsigned short u) {
  unsigned int v = ((unsigned int)u) << 16;
  return __builtin_bit_cast(float, v);
}
__device__ __forceinline__ unsigned short f2bf(float f) {
  unsigned int u = __builtin_bit_cast(unsigned int, f);
  unsigned int r = u + 0x7fffu + ((u >> 16) & 1u);
  return (unsigned short)(r >> 16);
}
__device__ __forceinline__ float lrelu(float v) { return v >= 0.f ? v : 0.2f * v; }

// -------- prep: F (fp32, 4096x512) -> X bf16 cols 0..511 of (4096,1024) --------
__global__ __launch_bounds__(256) void k_f_to_x(const float* __restrict__ F,
                                                unsigned short* __restrict__ X) {
  int idx = blockIdx.x * 256 + threadIdx.x;
  if (idx >= NTOK * DD) return;
  int t = idx >> 9, c = idx & 511;
  X[t * D2 + c] = f2bf(F[idx]);
}

// -------- prep: transpose (K,N) fp32 -> (N,K) bf16 --------
__global__ __launch_bounds__(256) void k_transpose_bf16(const float* __restrict__ in,
                                                        unsigned short* __restrict__ out,
                                                        int K, int N) {
  int idx = blockIdx.x * 256 + threadIdx.x;
  if (idx >= K * N) return;
  int n = idx / K, k = idx - n * K;
  out[idx] = f2bf(in[k * N + n]);
}

// -------- GEMM1: AC[t][n] = sum_k F[t][k] * W1ab[k][n], (4096 x 1024), bf16 out --------
__global__ __launch_bounds__(512) void k_gemm_ac(const unsigned short* __restrict__ X,
                                                 const unsigned short* __restrict__ W1abT,
                                                 unsigned short* __restrict__ AC) {
  const int tid = threadIdx.x;
  const int lane = tid & 63, wid = tid >> 6;
  const int wm = wid >> 2, wn = wid & 3;
  const int l15 = lane & 15, lk = (lane >> 4) << 3;
  const int rowbase = blockIdx.x * 64 + wm * 32;
  const int colbase = blockIdx.y * 128 + wn * 32;

  f32x4 acc[2][2];
#pragma unroll
  for (int mt = 0; mt < 2; ++mt)
#pragma unroll
    for (int nt = 0; nt < 2; ++nt) acc[mt][nt] = f32x4{0.f, 0.f, 0.f, 0.f};

  for (int kk = 0; kk < 512; kk += 32) {
    bf16x8 a[2], b[2];
#pragma unroll
    for (int mt = 0; mt < 2; ++mt)
      a[mt] = *reinterpret_cast<const bf16x8*>(X + (rowbase + mt * 16 + l15) * D2 + kk + lk);
#pragma unroll
    for (int nt = 0; nt < 2; ++nt)
      b[nt] = *reinterpret_cast<const bf16x8*>(W1abT + (colbase + nt * 16 + l15) * DD + kk + lk);
#pragma unroll
    for (int mt = 0; mt < 2; ++mt)
#pragma unroll
      for (int nt = 0; nt < 2; ++nt)
        acc[mt][nt] = __builtin_amdgcn_mfma_f32_16x16x32_bf16(a[mt], b[nt], acc[mt][nt], 0, 0, 0);
  }
#pragma unroll
  for (int mt = 0; mt < 2; ++mt)
#pragma unroll
    for (int nt = 0; nt < 2; ++nt) {
      int col = colbase + nt * 16 + l15;
#pragma unroll
      for (int r = 0; r < 4; ++r) {
        int row = rowbase + mt * 16 + (lane >> 4) * 4 + r;
        AC[row * D2 + col] = f2bf(acc[mt][nt][r]);
      }
    }
}

// -------- relation kernel: per block = (b, group of 4 i's), 64 rows --------
__global__ __launch_bounds__(512) void k_relation(const unsigned short* __restrict__ AC,
                                                  const unsigned short* __restrict__ W2T,
                                                  const unsigned short* __restrict__ W3T,
                                                  const float* __restrict__ b1,
                                                  const float* __restrict__ b2,
                                                  const float* __restrict__ b3,
                                                  unsigned short* __restrict__ X) {
  __shared__ unsigned short lds[64 * 512];  // 64 KB, XOR-swizzled rows
  const int tid = threadIdx.x;
  const int b = blockIdx.x >> 2, ig = blockIdx.x & 3;

  // ---- phase 0: h1 = lrelu(A_i + C_j + b1) -> LDS (bf16, swizzled) ----
  {
    const int r = tid >> 3;            // 0..63 : row = i_local*16 + j
    const int il = r >> 4, j = r & 15;
    const int tA = ((b << 4) + (ig << 2) + il) * D2;
    const int tC = ((b << 4) + j) * D2 + DD;
    const int c0 = (tid & 7) * 8;
#pragma unroll
    for (int cc = 0; cc < 512; cc += 64) {
      const int c = c0 + cc;
      uint4 av = *reinterpret_cast<const uint4*>(AC + tA + c);
      uint4 cv = *reinterpret_cast<const uint4*>(AC + tC + c);
      float4 bv0 = *reinterpret_cast<const float4*>(b1 + c);
      float4 bv1 = *reinterpret_cast<const float4*>(b1 + c + 4);
      unsigned int au[4] = {av.x, av.y, av.z, av.w};
      unsigned int cu[4] = {cv.x, cv.y, cv.z, cv.w};
      float bb[8] = {bv0.x, bv0.y, bv0.z, bv0.w, bv1.x, bv1.y, bv1.z, bv1.w};
      unsigned int ou[4];
#pragma unroll
      for (int q = 0; q < 4; ++q) {
        float v0 = lrelu(bf2f((unsigned short)(au[q] & 0xffffu)) +
                         bf2f((unsigned short)(cu[q] & 0xffffu)) + bb[2 * q]);
        float v1 = lrelu(bf2f((unsigned short)(au[q] >> 16)) +
                         bf2f((unsigned short)(cu[q] >> 16)) + bb[2 * q + 1]);
        ou[q] = ((unsigned int)f2bf(v1) << 16) | (unsigned int)f2bf(v0);
      }
      unsigned int byte = (unsigned int)(c * 2) ^ (unsigned int)((r & 7) << 4);
      uint4 o; o.x = ou[0]; o.y = ou[1]; o.z = ou[2]; o.w = ou[3];
      *reinterpret_cast<uint4*>(reinterpret_cast<char*>(lds) + r * 1024 + byte) = o;
    }
  }

  const int lane = tid & 63, wid = tid >> 6;
  const int wm = wid >> 2, wn = wid & 3;   // wave grid 2(M) x 4(N)
  const int l15 = lane & 15, lk = (lane >> 4) << 3;
  f32x4 acc[2][8];

  // ---- layer 2: h2 = lrelu(h1 @ W2 + b2) ----
  __syncthreads();
#pragma unroll
  for (int mt = 0; mt < 2; ++mt)
#pragma unroll
    for (int nt = 0; nt < 8; ++nt) acc[mt][nt] = f32x4{0.f, 0.f, 0.f, 0.f};
  for (int kk = 0; kk < 512; kk += 32) {
    bf16x8 a[2], bb[8];
#pragma unroll
    for (int mt = 0; mt < 2; ++mt) {
      int row = wm * 32 + mt * 16 + l15;
      unsigned int byte = (unsigned int)((kk + lk) * 2) ^ (unsigned int)((row & 7) << 4);
      a[mt] = *reinterpret_cast<const bf16x8*>(reinterpret_cast<const char*>(lds) + row * 1024 + byte);
    }
#pragma unroll
    for (int nt = 0; nt < 8; ++nt) {
      int n = wn * 128 + nt * 16 + l15;
      bb[nt] = *reinterpret_cast<const bf16x8*>(W2T + n * DD + kk + lk);
    }
#pragma unroll
    for (int mt = 0; mt < 2; ++mt)
#pragma unroll
      for (int nt = 0; nt < 8; ++nt)
        acc[mt][nt] = __builtin_amdgcn_mfma_f32_16x16x32_bf16(a[mt], bb[nt], acc[mt][nt], 0, 0, 0);
  }
  __syncthreads();  // everyone done reading h1; safe to overwrite in place
#pragma unroll
  for (int mt = 0; mt < 2; ++mt)
#pragma unroll
    for (int nt = 0; nt < 8; ++nt) {
      int col = wn * 128 + nt * 16 + l15;
      float bias = b2[col];
#pragma unroll
      for (int r = 0; r < 4; ++r) {
        int row = wm * 32 + mt * 16 + (lane >> 4) * 4 + r;
        float v = lrelu(acc[mt][nt][r] + bias);
        unsigned int byte = (unsigned int)(col * 2) ^ (unsigned int)((row & 7) << 4);
        *reinterpret_cast<unsigned short*>(reinterpret_cast<char*>(lds) + row * 1024 + byte) = f2bf(v);
      }
    }
  __syncthreads();

  // ---- layer 3: h3 = lrelu(h2 @ W3 + b3); sum over j -> Msum ----
#pragma unroll
  for (int mt = 0; mt < 2; ++mt)
#pragma unroll
    for (int nt = 0; nt < 8; ++nt) acc[mt][nt] = f32x4{0.f, 0.f, 0.f, 0.f};
  for (int kk = 0; kk < 512; kk += 32) {
    bf16x8 a[2], bb[8];
#pragma unroll
    for (int mt = 0; mt < 2; ++mt) {
      int row = wm * 32 + mt * 16 + l15;
      unsigned int byte = (unsigned int)((kk + lk) * 2) ^ (unsigned int)((row & 7) << 4);
      a[mt] = *reinterpret_cast<const bf16x8*>(reinterpret_cast<const char*>(lds) + row * 1024 + byte);
    }
#pragma unroll
    for (int nt = 0; nt < 8; ++nt) {
      int n = wn * 128 + nt * 16 + l15;
      bb[nt] = *reinterpret_cast<const bf16x8*>(W3T + n * DD + kk + lk);
    }
#pragma unroll
    for (int mt = 0; mt < 2; ++mt)
#pragma unroll
      for (int nt = 0; nt < 8; ++nt)
        acc[mt][nt] = __builtin_amdgcn_mfma_f32_16x16x32_bf16(a[mt], bb[nt], acc[mt][nt], 0, 0, 0);
  }
#pragma unroll
  for (int mt = 0; mt < 2; ++mt)
#pragma unroll
    for (int nt = 0; nt < 8; ++nt) {
      int col = wn * 128 + nt * 16 + l15;
      float bias = b3[col];
      float s = 0.f;
#pragma unroll
      for (int r = 0; r < 4; ++r) s += lrelu(acc[mt][nt][r] + bias);
      s += __shfl_xor(s, 16);
      s += __shfl_xor(s, 32);
      if (lane < 16) {
        int t = (b << 4) + (ig << 2) + wm * 2 + mt;   // each 16-row M-tile = one i
        X[t * D2 + DD + col] = f2bf(s);               // Msum (bf16) into X cols 512..1023
      }
    }
}

// -------- fusion GEMM: y = X @ Wf + bf (fp32 out) --------
__global__ __launch_bounds__(512) void k_fusion(const unsigned short* __restrict__ X,
                                                const unsigned short* __restrict__ WfT,
                                                const float* __restrict__ bfv,
                                                float* __restrict__ y) {
  const int tid = threadIdx.x;
  const int lane = tid & 63, wid = tid >> 6;
  const int wm = wid >> 2, wn = wid & 3;
  const int l15 = lane & 15, lk = (lane >> 4) << 3;
  const int rowbase = blockIdx.x * 64 + wm * 32;
  const int colbase = blockIdx.y * 128 + wn * 32;

  f32x4 acc[2][2];
#pragma unroll
  for (int mt = 0; mt < 2; ++mt)
#pragma unroll
    for (int nt = 0; nt < 2; ++nt) acc[mt][nt] = f32x4{0.f, 0.f, 0.f, 0.f};

  for (int kk = 0; kk < 1024; kk += 32) {
    bf16x8 a[2], b[2];
#pragma unroll
    for (int mt = 0; mt < 2; ++mt)
      a[mt] = *reinterpret_cast<const bf16x8*>(X + (rowbase + mt * 16 + l15) * D2 + kk + lk);
#pragma unroll
    for (int nt = 0; nt < 2; ++nt)
      b[nt] = *reinterpret_cast<const bf16x8*>(WfT + (colbase + nt * 16 + l15) * D2 + kk + lk);
#pragma unroll
    for (int mt = 0; mt < 2; ++mt)
#pragma unroll
      for (int nt = 0; nt < 2; ++nt)
        acc[mt][nt] = __builtin_amdgcn_mfma_f32_16x16x32_bf16(a[mt], b[nt], acc[mt][nt], 0, 0, 0);
  }
#pragma unroll
  for (int mt = 0; mt < 2; ++mt)
#pragma unroll
    for (int nt = 0; nt < 2; ++nt) {
      int col = colbase + nt * 16 + l15;
      float bias = bfv[col];
#pragma unroll
      for (int r = 0; r < 4; ++r) {
        int row = rowbase + mt * 16 + (lane >> 4) * 4 + r;
        y[row * DD + col] = acc[mt][nt][r] + bias;
      }
    }
}

// -------- BN stats: column sums / sumsq over 4096 rows --------
__global__ __launch_bounds__(256) void k_bnstats(const float* __restrict__ y,
                                                 float* __restrict__ sums,
                                                 float* __restrict__ sumsq) {
  const int tid = threadIdx.x;
  const int r0 = blockIdx.x * 64;
  float s0 = 0.f, s1 = 0.f, q0 = 0.f, q1 = 0.f;
  for (int r = 0; r < 64; ++r) {
    float v0 = y[(r0 + r) * DD + tid];
    float v1 = y[(r0 + r) * DD + tid + 256];
    s0 += v0; q0 += v0 * v0;
    s1 += v1; q1 += v1 * v1;
  }
  atomicAdd(&sums[tid], s0);
  atomicAdd(&sums[tid + 256], s1);
  atomicAdd(&sumsq[tid], q0);
  atomicAdd(&sumsq[tid + 256], q1);
}

// -------- BN apply + lrelu --------
__global__ __launch_bounds__(256) void k_bnapply(const float* __restrict__ y,
                                                 const float* __restrict__ sums,
                                                 const float* __restrict__ sumsq,
                                                 const float* __restrict__ gamma,
                                                 const float* __restrict__ beta,
                                                 float* __restrict__ out) {
  int idx = blockIdx.x * 256 + threadIdx.x;
  if (idx >= NTOK * DD) return;
  int c = idx & 511;
  float mean = sums[c] * (1.0f / 4096.0f);
  float var = sumsq[c] * (1.0f / 4096.0f) - mean * mean;
  float rstd = rsqrtf(var + 1e-5f);
  float v = (y[idx] - mean) * rstd * gamma[c] + beta[c];
  out[idx] = lrelu(v);
}

extern "C" void kernel_launch(void* const* d_in, const int* in_sizes, int n_in,
                              void* d_out, int out_size, void* d_ws, size_t ws_size,
                              hipStream_t stream) {
  const float* F   = (const float*)d_in[0];
  const float* W1  = (const float*)d_in[1];
  const float* b1  = (const float*)d_in[2];
  const float* W2  = (const float*)d_in[3];
  const float* b2  = (const float*)d_in[4];
  const float* W3  = (const float*)d_in[5];
  const float* b3  = (const float*)d_in[6];
  const float* Wf  = (const float*)d_in[7];
  const float* bfv = (const float*)d_in[8];
  const float* gamma = (const float*)d_in[9];
  const float* beta  = (const float*)d_in[10];
  float* out = (float*)d_out;

  char* ws = (char*)d_ws;
  unsigned short* X     = (unsigned short*)(ws);                              // 8 MB: [F | Msum] bf16
  unsigned short* AC    = (unsigned short*)(ws + (8u << 20));                 // 8 MB
  unsigned short* W1abT = (unsigned short*)(ws + (16u << 20));                // 1 MB
  unsigned short* W2T   = (unsigned short*)(ws + (17u << 20));                // 0.5 MB
  unsigned short* W3T   = (unsigned short*)(ws + (17u << 20) + (512u << 10)); // 0.5 MB
  unsigned short* WfT   = (unsigned short*)(ws + (18u << 20));                // 1 MB
  float* y              = (float*)(ws + (19u << 20));                         // 8 MB
  float* sums           = (float*)(ws + (27u << 20));                         // 2 KB
  float* sumsq          = sums + 512;                                         // 2 KB

  hipMemsetAsync(sums, 0, 1024 * sizeof(float), stream);

  k_f_to_x<<<(NTOK * DD + 255) / 256, 256, 0, stream>>>(F, X);
  k_transpose_bf16<<<(512 * 512 + 255) / 256, 256, 0, stream>>>(W1, W1abT, 512, 512);
  k_transpose_bf16<<<(512 * 512 + 255) / 256, 256, 0, stream>>>(W1 + 512 * 512, W1abT + 512 * 512, 512, 512);
  k_transpose_bf16<<<(512 * 512 + 255) / 256, 256, 0, stream>>>(W2, W2T, 512, 512);
  k_transpose_bf16<<<(512 * 512 + 255) / 256, 256, 0, stream>>>(W3, W3T, 512, 512);
  k_transpose_bf16<<<(1024 * 512 + 255) / 256, 256, 0, stream>>>(Wf, WfT, 1024, 512);

  k_gemm_ac<<<dim3(64, 8), 512, 0, stream>>>(X, W1abT, AC);
  k_relation<<<1024, 512, 0, stream>>>(AC, W2T, W3T, b1, b2, b3, X);
  k_fusion<<<dim3(64, 4), 512, 0, stream>>>(X, WfT, bfv, y);
  k_bnstats<<<64, 256, 0, stream>>>(y, sums, sumsq);
  k_bnapply<<<(NTOK * DD + 255) / 256, 256, 0, stream>>>(y, sums, sumsq, gamma, beta, out);
}

// Round 2
// 181.013 us; speedup vs baseline: 1.9964x; 1.9964x over previous
//
#include <hip/hip_runtime.h>

using f32x4  = __attribute__((ext_vector_type(4))) float;
using bf16x8 = __attribute__((ext_vector_type(8))) __bf16;

static constexpr int DD = 512;
static constexpr int D2 = 1024;
static constexpr int NTOK = 4096;  // B*V

__device__ __forceinline__ float bf2f(unsigned short u) {
  unsigned int v = ((unsigned int)u) << 16;
  return __builtin_bit_cast(float, v);
}
__device__ __forceinline__ unsigned short f2bf(float f) {
  unsigned int u = __builtin_bit_cast(unsigned int, f);
  unsigned int r = u + 0x7fffu + ((u >> 16) & 1u);
  return (unsigned short)(r >> 16);
}
__device__ __forceinline__ float lrelu(float v) { return v >= 0.f ? v : 0.2f * v; }

// -------- prep: F (fp32, 4096x512) -> X bf16 cols 0..511 of (4096,1024) --------
__global__ __launch_bounds__(256) void k_f_to_x(const float* __restrict__ F,
                                                unsigned short* __restrict__ X) {
  int idx = blockIdx.x * 256 + threadIdx.x;
  if (idx >= NTOK * DD) return;
  int t = idx >> 9, c = idx & 511;
  X[t * D2 + c] = f2bf(F[idx]);
}

// -------- prep: transpose (K,N) fp32 -> (N,K) bf16 (for k_gemm_ac / k_fusion) --------
__global__ __launch_bounds__(256) void k_transpose_bf16(const float* __restrict__ in,
                                                        unsigned short* __restrict__ out,
                                                        int K, int N) {
  int idx = blockIdx.x * 256 + threadIdx.x;
  if (idx >= K * N) return;
  int n = idx / K, k = idx - n * K;
  out[idx] = f2bf(in[k * N + n]);
}

// -------- prep: pack (K,N) fp32 weight into 16x16x32 MFMA B-fragment order --------
// tile (16 cols x 32 k): tile_idx = (n>>4)*(K>>5) + (k>>5)
// within tile (512 bf16 = one wave's 16B/lane): lane = ((k>>3)&3)*16 + (n&15), elem = k&7
__global__ __launch_bounds__(256) void k_pack_w16(const float* __restrict__ in,
                                                  unsigned short* __restrict__ out,
                                                  int K, int N) {
  int idx = blockIdx.x * 256 + threadIdx.x;
  if (idx >= K * N) return;
  int k = idx / N, n = idx - k * N;
  int tile = (n >> 4) * (K >> 5) + (k >> 5);
  int off = tile * 512 + ((k >> 3) & 3) * 128 + (n & 15) * 8 + (k & 7);
  out[off] = f2bf(in[idx]);
}

// -------- GEMM1: AC[t][n] = sum_k F[t][k] * W1ab[k][n], (4096 x 1024), bf16 out --------
__global__ __launch_bounds__(512) void k_gemm_ac(const unsigned short* __restrict__ X,
                                                 const unsigned short* __restrict__ W1abT,
                                                 unsigned short* __restrict__ AC) {
  const int tid = threadIdx.x;
  const int lane = tid & 63, wid = tid >> 6;
  const int wm = wid >> 2, wn = wid & 3;
  const int l15 = lane & 15, lk = (lane >> 4) << 3;
  const int rowbase = blockIdx.x * 64 + wm * 32;
  const int colbase = blockIdx.y * 128 + wn * 32;

  f32x4 acc[2][2];
#pragma unroll
  for (int mt = 0; mt < 2; ++mt)
#pragma unroll
    for (int nt = 0; nt < 2; ++nt) acc[mt][nt] = f32x4{0.f, 0.f, 0.f, 0.f};

  for (int kk = 0; kk < 512; kk += 32) {
    bf16x8 a[2], b[2];
#pragma unroll
    for (int mt = 0; mt < 2; ++mt)
      a[mt] = *reinterpret_cast<const bf16x8*>(X + (rowbase + mt * 16 + l15) * D2 + kk + lk);
#pragma unroll
    for (int nt = 0; nt < 2; ++nt)
      b[nt] = *reinterpret_cast<const bf16x8*>(W1abT + (colbase + nt * 16 + l15) * DD + kk + lk);
#pragma unroll
    for (int mt = 0; mt < 2; ++mt)
#pragma unroll
      for (int nt = 0; nt < 2; ++nt)
        acc[mt][nt] = __builtin_amdgcn_mfma_f32_16x16x32_bf16(a[mt], b[nt], acc[mt][nt], 0, 0, 0);
  }
#pragma unroll
  for (int mt = 0; mt < 2; ++mt)
#pragma unroll
    for (int nt = 0; nt < 2; ++nt) {
      int col = colbase + nt * 16 + l15;
#pragma unroll
      for (int r = 0; r < 4; ++r) {
        int row = rowbase + mt * 16 + (lane >> 4) * 4 + r;
        AC[row * D2 + col] = f2bf(acc[mt][nt][r]);
      }
    }
}

// -------- relation kernel: per block = (b, group of 4 i's), 64 rows --------
// wave grid 1x8: each wave owns all 64 rows x 64 cols (4 m-tiles x 4 n-tiles).
// B-operand from packed fragment layout -> coalesced lane*16B loads.
__global__ __launch_bounds__(512) void k_relation(const unsigned short* __restrict__ AC,
                                                  const unsigned short* __restrict__ W2P,
                                                  const unsigned short* __restrict__ W3P,
                                                  const float* __restrict__ b1,
                                                  const float* __restrict__ b2,
                                                  const float* __restrict__ b3,
                                                  unsigned short* __restrict__ X) {
  __shared__ unsigned short lds[64 * 512];  // 64 KB, XOR-swizzled rows
  const int tid = threadIdx.x;
  const int b = blockIdx.x >> 2, ig = blockIdx.x & 3;

  // ---- phase 0: h1 = lrelu(A_i + C_j + b1) -> LDS (bf16, swizzled) ----
  {
    const int r = tid >> 3;            // 0..63 : row = i_local*16 + j
    const int il = r >> 4, j = r & 15;
    const int tA = ((b << 4) + (ig << 2) + il) * D2;
    const int tC = ((b << 4) + j) * D2 + DD;
    const int c0 = (tid & 7) * 8;
#pragma unroll
    for (int cc = 0; cc < 512; cc += 64) {
      const int c = c0 + cc;
      uint4 av = *reinterpret_cast<const uint4*>(AC + tA + c);
      uint4 cv = *reinterpret_cast<const uint4*>(AC + tC + c);
      float4 bv0 = *reinterpret_cast<const float4*>(b1 + c);
      float4 bv1 = *reinterpret_cast<const float4*>(b1 + c + 4);
      unsigned int au[4] = {av.x, av.y, av.z, av.w};
      unsigned int cu[4] = {cv.x, cv.y, cv.z, cv.w};
      float bb[8] = {bv0.x, bv0.y, bv0.z, bv0.w, bv1.x, bv1.y, bv1.z, bv1.w};
      unsigned int ou[4];
#pragma unroll
      for (int q = 0; q < 4; ++q) {
        float v0 = lrelu(bf2f((unsigned short)(au[q] & 0xffffu)) +
                         bf2f((unsigned short)(cu[q] & 0xffffu)) + bb[2 * q]);
        float v1 = lrelu(bf2f((unsigned short)(au[q] >> 16)) +
                         bf2f((unsigned short)(cu[q] >> 16)) + bb[2 * q + 1]);
        ou[q] = ((unsigned int)f2bf(v1) << 16) | (unsigned int)f2bf(v0);
      }
      unsigned int byte = (unsigned int)(c * 2) ^ (unsigned int)((r & 7) << 4);
      uint4 o; o.x = ou[0]; o.y = ou[1]; o.z = ou[2]; o.w = ou[3];
      *reinterpret_cast<uint4*>(reinterpret_cast<char*>(lds) + r * 1024 + byte) = o;
    }
  }

  const int lane = tid & 63, wid = tid >> 6;   // wid = wn slice (0..7)
  const int l15 = lane & 15, lk = (lane >> 4) << 3;

  auto ldA = [&](bf16x8 (&d)[4], int KK) {
#pragma unroll
    for (int mt = 0; mt < 4; ++mt) {
      int row = mt * 16 + l15;
      unsigned int byte = (unsigned int)((KK + lk) * 2) ^ (unsigned int)((row & 7) << 4);
      d[mt] = *reinterpret_cast<const bf16x8*>(reinterpret_cast<const char*>(lds) + row * 1024 + byte);
    }
  };
  auto ldB = [&](bf16x8 (&d)[4], const unsigned short* __restrict__ Wp, int KK) {
#pragma unroll
    for (int nt = 0; nt < 4; ++nt)
      d[nt] = *reinterpret_cast<const bf16x8*>(Wp + (((wid * 4 + nt) * 16 + (KK >> 5)) << 9) + lane * 8);
  };

  f32x4 acc[4][4];
  bf16x8 ca[4], cb[4], na[4], nb[4];

  // ---- layer 2: h2 = lrelu(h1 @ W2 + b2) ----
  __syncthreads();
#pragma unroll
  for (int mt = 0; mt < 4; ++mt)
#pragma unroll
    for (int nt = 0; nt < 4; ++nt) acc[mt][nt] = f32x4{0.f, 0.f, 0.f, 0.f};
  ldA(ca, 0); ldB(cb, W2P, 0);
  for (int kk = 0; kk < 512; kk += 32) {
    int kn = (kk + 32) & 511;
    ldB(nb, W2P, kn);
    ldA(na, kn);
    __builtin_amdgcn_s_setprio(1);
#pragma unroll
    for (int mt = 0; mt < 4; ++mt)
#pragma unroll
      for (int nt = 0; nt < 4; ++nt)
        acc[mt][nt] = __builtin_amdgcn_mfma_f32_16x16x32_bf16(ca[mt], cb[nt], acc[mt][nt], 0, 0, 0);
    __builtin_amdgcn_s_setprio(0);
#pragma unroll
    for (int q = 0; q < 4; ++q) { ca[q] = na[q]; cb[q] = nb[q]; }
  }
  __syncthreads();  // all waves done reading h1; safe to overwrite in place
#pragma unroll
  for (int mt = 0; mt < 4; ++mt)
#pragma unroll
    for (int nt = 0; nt < 4; ++nt) {
      int col = wid * 64 + nt * 16 + l15;
      float bias = b2[col];
#pragma unroll
      for (int r = 0; r < 4; ++r) {
        int row = mt * 16 + (lane >> 4) * 4 + r;
        float v = lrelu(acc[mt][nt][r] + bias);
        unsigned int byte = (unsigned int)(col * 2) ^ (unsigned int)((row & 7) << 4);
        *reinterpret_cast<unsigned short*>(reinterpret_cast<char*>(lds) + row * 1024 + byte) = f2bf(v);
      }
    }
  __syncthreads();

  // ---- layer 3: h3 = lrelu(h2 @ W3 + b3); sum over j -> Msum ----
#pragma unroll
  for (int mt = 0; mt < 4; ++mt)
#pragma unroll
    for (int nt = 0; nt < 4; ++nt) acc[mt][nt] = f32x4{0.f, 0.f, 0.f, 0.f};
  ldA(ca, 0); ldB(cb, W3P, 0);
  for (int kk = 0; kk < 512; kk += 32) {
    int kn = (kk + 32) & 511;
    ldB(nb, W3P, kn);
    ldA(na, kn);
    __builtin_amdgcn_s_setprio(1);
#pragma unroll
    for (int mt = 0; mt < 4; ++mt)
#pragma unroll
      for (int nt = 0; nt < 4; ++nt)
        acc[mt][nt] = __builtin_amdgcn_mfma_f32_16x16x32_bf16(ca[mt], cb[nt], acc[mt][nt], 0, 0, 0);
    __builtin_amdgcn_s_setprio(0);
#pragma unroll
    for (int q = 0; q < 4; ++q) { ca[q] = na[q]; cb[q] = nb[q]; }
  }
#pragma unroll
  for (int mt = 0; mt < 4; ++mt)
#pragma unroll
    for (int nt = 0; nt < 4; ++nt) {
      int col = wid * 64 + nt * 16 + l15;
      float bias = b3[col];
      float s = 0.f;
#pragma unroll
      for (int r = 0; r < 4; ++r) s += lrelu(acc[mt][nt][r] + bias);
      s += __shfl_xor(s, 16);
      s += __shfl_xor(s, 32);
      if (lane < 16) {
        int t = (b << 4) + (ig << 2) + mt;   // each 16-row m-tile = one i
        X[t * D2 + DD + col] = f2bf(s);      // Msum (bf16) into X cols 512..1023
      }
    }
}

// -------- fusion GEMM: y = X @ Wf + bf (fp32 out) --------
__global__ __launch_bounds__(512) void k_fusion(const unsigned short* __restrict__ X,
                                                const unsigned short* __restrict__ WfT,
                                                const float* __restrict__ bfv,
                                                float* __restrict__ y) {
  const int tid = threadIdx.x;
  const int lane = tid & 63, wid = tid >> 6;
  const int wm = wid >> 2, wn = wid & 3;
  const int l15 = lane & 15, lk = (lane >> 4) << 3;
  const int rowbase = blockIdx.x * 64 + wm * 32;
  const int colbase = blockIdx.y * 128 + wn * 32;

  f32x4 acc[2][2];
#pragma unroll
  for (int mt = 0; mt < 2; ++mt)
#pragma unroll
    for (int nt = 0; nt < 2; ++nt) acc[mt][nt] = f32x4{0.f, 0.f, 0.f, 0.f};

  for (int kk = 0; kk < 1024; kk += 32) {
    bf16x8 a[2], b[2];
#pragma unroll
    for (int mt = 0; mt < 2; ++mt)
      a[mt] = *reinterpret_cast<const bf16x8*>(X + (rowbase + mt * 16 + l15) * D2 + kk + lk);
#pragma unroll
    for (int nt = 0; nt < 2; ++nt)
      b[nt] = *reinterpret_cast<const bf16x8*>(WfT + (colbase + nt * 16 + l15) * D2 + kk + lk);
#pragma unroll
    for (int mt = 0; mt < 2; ++mt)
#pragma unroll
      for (int nt = 0; nt < 2; ++nt)
        acc[mt][nt] = __builtin_amdgcn_mfma_f32_16x16x32_bf16(a[mt], b[nt], acc[mt][nt], 0, 0, 0);
  }
#pragma unroll
  for (int mt = 0; mt < 2; ++mt)
#pragma unroll
    for (int nt = 0; nt < 2; ++nt) {
      int col = colbase + nt * 16 + l15;
      float bias = bfv[col];
#pragma unroll
      for (int r = 0; r < 4; ++r) {
        int row = rowbase + mt * 16 + (lane >> 4) * 4 + r;
        y[row * DD + col] = acc[mt][nt][r] + bias;
      }
    }
}

// -------- BN stats: column sums / sumsq over 4096 rows --------
__global__ __launch_bounds__(256) void k_bnstats(const float* __restrict__ y,
                                                 float* __restrict__ sums,
                                                 float* __restrict__ sumsq) {
  const int tid = threadIdx.x;
  const int r0 = blockIdx.x * 64;
  float s0 = 0.f, s1 = 0.f, q0 = 0.f, q1 = 0.f;
  for (int r = 0; r < 64; ++r) {
    float v0 = y[(r0 + r) * DD + tid];
    float v1 = y[(r0 + r) * DD + tid + 256];
    s0 += v0; q0 += v0 * v0;
    s1 += v1; q1 += v1 * v1;
  }
  atomicAdd(&sums[tid], s0);
  atomicAdd(&sums[tid + 256], s1);
  atomicAdd(&sumsq[tid], q0);
  atomicAdd(&sumsq[tid + 256], q1);
}

// -------- BN apply + lrelu --------
__global__ __launch_bounds__(256) void k_bnapply(const float* __restrict__ y,
                                                 const float* __restrict__ sums,
                                                 const float* __restrict__ sumsq,
                                                 const float* __restrict__ gamma,
                                                 const float* __restrict__ beta,
                                                 float* __restrict__ out) {
  int idx = blockIdx.x * 256 + threadIdx.x;
  if (idx >= NTOK * DD) return;
  int c = idx & 511;
  float mean = sums[c] * (1.0f / 4096.0f);
  float var = sumsq[c] * (1.0f / 4096.0f) - mean * mean;
  float rstd = rsqrtf(var + 1e-5f);
  float v = (y[idx] - mean) * rstd * gamma[c] + beta[c];
  out[idx] = lrelu(v);
}

extern "C" void kernel_launch(void* const* d_in, const int* in_sizes, int n_in,
                              void* d_out, int out_size, void* d_ws, size_t ws_size,
                              hipStream_t stream) {
  const float* F   = (const float*)d_in[0];
  const float* W1  = (const float*)d_in[1];
  const float* b1  = (const float*)d_in[2];
  const float* W2  = (const float*)d_in[3];
  const float* b2  = (const float*)d_in[4];
  const float* W3  = (const float*)d_in[5];
  const float* b3  = (const float*)d_in[6];
  const float* Wf  = (const float*)d_in[7];
  const float* bfv = (const float*)d_in[8];
  const float* gamma = (const float*)d_in[9];
  const float* beta  = (const float*)d_in[10];
  float* out = (float*)d_out;

  char* ws = (char*)d_ws;
  unsigned short* X     = (unsigned short*)(ws);                              // 8 MB: [F | Msum] bf16
  unsigned short* AC    = (unsigned short*)(ws + (8u << 20));                 // 8 MB
  unsigned short* W1abT = (unsigned short*)(ws + (16u << 20));                // 1 MB
  unsigned short* W2P   = (unsigned short*)(ws + (17u << 20));                // 0.5 MB (packed frags)
  unsigned short* W3P   = (unsigned short*)(ws + (17u << 20) + (512u << 10)); // 0.5 MB (packed frags)
  unsigned short* WfT   = (unsigned short*)(ws + (18u << 20));                // 1 MB
  float* y              = (float*)(ws + (19u << 20));                         // 8 MB
  float* sums           = (float*)(ws + (27u << 20));                         // 2 KB
  float* sumsq          = sums + 512;                                         // 2 KB

  hipMemsetAsync(sums, 0, 1024 * sizeof(float), stream);

  k_f_to_x<<<(NTOK * DD + 255) / 256, 256, 0, stream>>>(F, X);
  k_transpose_bf16<<<(512 * 512 + 255) / 256, 256, 0, stream>>>(W1, W1abT, 512, 512);
  k_transpose_bf16<<<(512 * 512 + 255) / 256, 256, 0, stream>>>(W1 + 512 * 512, W1abT + 512 * 512, 512, 512);
  k_pack_w16<<<(512 * 512 + 255) / 256, 256, 0, stream>>>(W2, W2P, 512, 512);
  k_pack_w16<<<(512 * 512 + 255) / 256, 256, 0, stream>>>(W3, W3P, 512, 512);
  k_transpose_bf16<<<(1024 * 512 + 255) / 256, 256, 0, stream>>>(Wf, WfT, 1024, 512);

  k_gemm_ac<<<dim3(64, 8), 512, 0, stream>>>(X, W1abT, AC);
  k_relation<<<1024, 512, 0, stream>>>(AC, W2P, W3P, b1, b2, b3, X);
  k_fusion<<<dim3(64, 4), 512, 0, stream>>>(X, WfT, bfv, y);
  k_bnstats<<<64, 256, 0, stream>>>(y, sums, sumsq);
  k_bnapply<<<(NTOK * DD + 255) / 256, 256, 0, stream>>>(y, sums, sumsq, gamma, beta, out);
}

// Round 3
// 123.827 us; speedup vs baseline: 2.9184x; 1.4618x over previous
//
#include <hip/hip_runtime.h>

using f32x4  = __attribute__((ext_vector_type(4))) float;
using bf16x8 = __attribute__((ext_vector_type(8))) __bf16;

static constexpr int DD = 512;
static constexpr int NTOK = 4096;  // B*V

__device__ __forceinline__ float bf2f(unsigned short u) {
  unsigned int v = ((unsigned int)u) << 16;
  return __builtin_bit_cast(float, v);
}
__device__ __forceinline__ unsigned short f2bf(float f) {
  unsigned int u = __builtin_bit_cast(unsigned int, f);
  unsigned int r = u + 0x7fffu + ((u >> 16) & 1u);
  return (unsigned short)(r >> 16);
}
__device__ __forceinline__ float lrelu(float v) { return v >= 0.f ? v : 0.2f * v; }

// Fragment-panel layout for an (M,K) matrix consumed as MFMA A-operand (or
// (K,N) consumed as B): off = (panel*KS + ks)*512 + kq*128 + row*8 + k0
// where panel = row16-tile, ks = k>>5, kq = (k>>3)&3, k0 = k&7.
// A wave's fragment load is then base + lane*8 (fully coalesced 1KB).

// ---- k_prep: all layout transforms + BN accumulator zeroing, one dispatch ----
__global__ __launch_bounds__(256) void k_prep(const float* __restrict__ F,
                                              const float* __restrict__ W1,
                                              const float* __restrict__ W2,
                                              const float* __restrict__ W3,
                                              const float* __restrict__ Wf,
                                              unsigned short* __restrict__ XP,
                                              unsigned short* __restrict__ W1P,
                                              unsigned short* __restrict__ W2P,
                                              unsigned short* __restrict__ W3P,
                                              unsigned short* __restrict__ WfP,
                                              float* __restrict__ sums) {
  const int bid = blockIdx.x, tid = threadIdx.x;
  if (bid < 8192) {                       // F -> XP (panel layout, K-dim 1024: F part ks 0..15)
    int idx = (bid << 8) + tid;           // 4096*512
    int t = idx >> 9, c = idx & 511;
    XP[((t >> 4) * 32 + (c >> 5)) * 512 + ((c >> 3) & 3) * 128 + (t & 15) * 8 + (c & 7)] = f2bf(F[idx]);
  } else if (bid < 10240) {               // W1 (1024,512) -> W1P fragment order (K=512, N=1024 combined)
    int idx = ((bid - 8192) << 8) + tid;  // 512*1024
    int k = idx >> 10, n = idx & 1023;
    float v = W1[(n < 512 ? k : 512 + k) * 512 + (n & 511)];
    W1P[((n >> 4) * 16 + (k >> 5)) * 512 + ((k >> 3) & 3) * 128 + (n & 15) * 8 + (k & 7)] = f2bf(v);
  } else if (bid < 11264) {               // W2 (512,512) -> W2P
    int idx = ((bid - 10240) << 8) + tid;
    int k = idx >> 9, n = idx & 511;
    W2P[((n >> 4) * 16 + (k >> 5)) * 512 + ((k >> 3) & 3) * 128 + (n & 15) * 8 + (k & 7)] = f2bf(W2[idx]);
  } else if (bid < 12288) {               // W3
    int idx = ((bid - 11264) << 8) + tid;
    int k = idx >> 9, n = idx & 511;
    W3P[((n >> 4) * 16 + (k >> 5)) * 512 + ((k >> 3) & 3) * 128 + (n & 15) * 8 + (k & 7)] = f2bf(W3[idx]);
  } else if (bid < 14336) {               // Wf (1024,512) -> WfP (K=1024)
    int idx = ((bid - 12288) << 8) + tid;
    int k = idx >> 9, n = idx & 511;
    WfP[((n >> 4) * 32 + (k >> 5)) * 512 + ((k >> 3) & 3) * 128 + (n & 15) * 8 + (k & 7)] = f2bf(Wf[idx]);
  } else {                                // zero sums+sumsq (1024 floats)
    reinterpret_cast<float4*>(sums)[tid] = float4{0.f, 0.f, 0.f, 0.f};
  }
}

// ---- GEMM1: ACP = [F@W1a | F@W1b] in panel layout. grid (64,4), 512 thr ----
__global__ __launch_bounds__(512) void k_gemm_ac(const unsigned short* __restrict__ XP,
                                                 const unsigned short* __restrict__ W1P,
                                                 unsigned short* __restrict__ ACP) {
  const int tid = threadIdx.x, lane = tid & 63, wid = tid >> 6;
  const int wm = wid >> 2, wn = wid & 3;
  const int l15 = lane & 15;
  const int bx = blockIdx.x, by = blockIdx.y;

  f32x4 acc[2][4];
#pragma unroll
  for (int mt = 0; mt < 2; ++mt)
#pragma unroll
    for (int nt = 0; nt < 4; ++nt) acc[mt][nt] = f32x4{0.f, 0.f, 0.f, 0.f};

  bf16x8 ca[2], cb[4], na[2], nb[4];
  auto ldA = [&](bf16x8 (&d)[2], int ks) {
#pragma unroll
    for (int mt = 0; mt < 2; ++mt)
      d[mt] = *reinterpret_cast<const bf16x8*>(XP + (((bx * 4 + wm * 2 + mt) * 32 + ks) << 9) + lane * 8);
  };
  auto ldB = [&](bf16x8 (&d)[4], int ks) {
#pragma unroll
    for (int nt = 0; nt < 4; ++nt)
      d[nt] = *reinterpret_cast<const bf16x8*>(W1P + ((((by * 16 + wn * 4 + nt) * 16) + ks) << 9) + lane * 8);
  };

  ldA(ca, 0); ldB(cb, 0);
  for (int ks = 0; ks < 16; ++ks) {
    int kn = (ks + 1) & 15;
    ldA(na, kn); ldB(nb, kn);
    __builtin_amdgcn_s_setprio(1);
#pragma unroll
    for (int mt = 0; mt < 2; ++mt)
#pragma unroll
      for (int nt = 0; nt < 4; ++nt)
        acc[mt][nt] = __builtin_amdgcn_mfma_f32_16x16x32_bf16(ca[mt], cb[nt], acc[mt][nt], 0, 0, 0);
    __builtin_amdgcn_s_setprio(0);
#pragma unroll
    for (int q = 0; q < 2; ++q) ca[q] = na[q];
#pragma unroll
    for (int q = 0; q < 4; ++q) cb[q] = nb[q];
  }
#pragma unroll
  for (int mt = 0; mt < 2; ++mt)
#pragma unroll
    for (int nt = 0; nt < 4; ++nt) {
      int col = by * 256 + wn * 64 + nt * 16 + l15;
      int panel = bx * 4 + wm * 2 + mt;
#pragma unroll
      for (int r = 0; r < 4; ++r) {
        int rowi = (lane >> 4) * 4 + r;
        ACP[(panel * 32 + (col >> 5)) * 512 + ((col >> 3) & 3) * 128 + rowi * 8 + (col & 7)] = f2bf(acc[mt][nt][r]);
      }
    }
}

// ---- relation: block = (b, half) -> 8 i's x 16 j's = 128 rows. 512 blocks ----
__global__ __launch_bounds__(512, 2) void k_relation(const unsigned short* __restrict__ ACP,
                                                     const unsigned short* __restrict__ W2P,
                                                     const unsigned short* __restrict__ W3P,
                                                     const float* __restrict__ b1,
                                                     const float* __restrict__ b2,
                                                     const float* __restrict__ b3,
                                                     unsigned short* __restrict__ XP) {
  __shared__ unsigned short lds[65536];  // 128 rows x 512 cols bf16 = 128 KB, XOR-swizzled
  const int tid = threadIdx.x;
  const int b = blockIdx.x >> 1, half = blockIdx.x & 1;

  // ---- phase 0: h1 = lrelu(A_i + C_j + b1) -> LDS ----
  {
    const int r = tid >> 2;              // 0..127 : row = i_local*16 + j
    const int il = r >> 4, j = r & 15;
    const int rowA = half * 8 + il;
    const int c0 = (tid & 3) * 8;
#pragma unroll
    for (int cc = 0; cc < 512; cc += 32) {
      const int c = c0 + cc;
      uint4 av = *reinterpret_cast<const uint4*>(ACP + ((b * 32 + (cc >> 5)) << 9) + (c0 >> 3) * 128 + rowA * 8);
      uint4 cv = *reinterpret_cast<const uint4*>(ACP + ((b * 32 + 16 + (cc >> 5)) << 9) + (c0 >> 3) * 128 + j * 8);
      float4 bv0 = *reinterpret_cast<const float4*>(b1 + c);
      float4 bv1 = *reinterpret_cast<const float4*>(b1 + c + 4);
      unsigned int au[4] = {av.x, av.y, av.z, av.w};
      unsigned int cu[4] = {cv.x, cv.y, cv.z, cv.w};
      float bb[8] = {bv0.x, bv0.y, bv0.z, bv0.w, bv1.x, bv1.y, bv1.z, bv1.w};
      unsigned int ou[4];
#pragma unroll
      for (int q = 0; q < 4; ++q) {
        float v0 = lrelu(bf2f((unsigned short)(au[q] & 0xffffu)) +
                         bf2f((unsigned short)(cu[q] & 0xffffu)) + bb[2 * q]);
        float v1 = lrelu(bf2f((unsigned short)(au[q] >> 16)) +
                         bf2f((unsigned short)(cu[q] >> 16)) + bb[2 * q + 1]);
        ou[q] = ((unsigned int)f2bf(v1) << 16) | (unsigned int)f2bf(v0);
      }
      unsigned int byte = (unsigned int)(c * 2) ^ (unsigned int)((r & 7) << 4);
      uint4 o; o.x = ou[0]; o.y = ou[1]; o.z = ou[2]; o.w = ou[3];
      *reinterpret_cast<uint4*>(reinterpret_cast<char*>(lds) + r * 1024 + byte) = o;
    }
  }

  const int lane = tid & 63, wid = tid >> 6;   // wid = col-slice 0..7 (64 cols each)
  const int l15 = lane & 15, lk = (lane >> 4) << 3;
  const unsigned int swz = (unsigned int)((l15 & 7) << 4);

  f32x4 acc[8][4];
  bf16x8 ca[4], cb[4], nb[4];

  auto ldB = [&](bf16x8 (&d)[4], const unsigned short* __restrict__ Wp, int ks) {
#pragma unroll
    for (int nt = 0; nt < 4; ++nt)
      d[nt] = *reinterpret_cast<const bf16x8*>(Wp + (((wid * 4 + nt) * 16 + ks) << 9) + lane * 8);
  };

  // ---- layer 2: h2 = lrelu(h1 @ W2 + b2), in-place in LDS ----
  __syncthreads();
#pragma unroll
  for (int mt = 0; mt < 8; ++mt)
#pragma unroll
    for (int nt = 0; nt < 4; ++nt) acc[mt][nt] = f32x4{0.f, 0.f, 0.f, 0.f};
  ldB(cb, W2P, 0);
  for (int ks = 0; ks < 16; ++ks) {
    ldB(nb, W2P, (ks + 1) & 15);
    unsigned int colb = (unsigned int)((ks * 32 + lk) * 2) ^ swz;
#pragma unroll
    for (int h = 0; h < 2; ++h) {
#pragma unroll
      for (int q = 0; q < 4; ++q) {
        int row = (h * 4 + q) * 16 + l15;
        ca[q] = *reinterpret_cast<const bf16x8*>(reinterpret_cast<const char*>(lds) + row * 1024 + colb);
      }
      __builtin_amdgcn_s_setprio(1);
#pragma unroll
      for (int q = 0; q < 4; ++q)
#pragma unroll
        for (int nt = 0; nt < 4; ++nt)
          acc[h * 4 + q][nt] = __builtin_amdgcn_mfma_f32_16x16x32_bf16(ca[q], cb[nt], acc[h * 4 + q][nt], 0, 0, 0);
      __builtin_amdgcn_s_setprio(0);
    }
#pragma unroll
    for (int q = 0; q < 4; ++q) cb[q] = nb[q];
  }
  __syncthreads();  // all waves done reading h1
#pragma unroll
  for (int mt = 0; mt < 8; ++mt)
#pragma unroll
    for (int nt = 0; nt < 4; ++nt) {
      int col = wid * 64 + nt * 16 + l15;
      float bias = b2[col];
#pragma unroll
      for (int r = 0; r < 4; ++r) {
        int row = mt * 16 + (lane >> 4) * 4 + r;
        float v = lrelu(acc[mt][nt][r] + bias);
        unsigned int byte = (unsigned int)(col * 2) ^ (unsigned int)((row & 7) << 4);
        *reinterpret_cast<unsigned short*>(reinterpret_cast<char*>(lds) + row * 1024 + byte) = f2bf(v);
      }
    }
  __syncthreads();

  // ---- layer 3: h3 = lrelu(h2 @ W3 + b3); j-sum -> Msum into XP ----
#pragma unroll
  for (int mt = 0; mt < 8; ++mt)
#pragma unroll
    for (int nt = 0; nt < 4; ++nt) acc[mt][nt] = f32x4{0.f, 0.f, 0.f, 0.f};
  ldB(cb, W3P, 0);
  for (int ks = 0; ks < 16; ++ks) {
    ldB(nb, W3P, (ks + 1) & 15);
    unsigned int colb = (unsigned int)((ks * 32 + lk) * 2) ^ swz;
#pragma unroll
    for (int h = 0; h < 2; ++h) {
#pragma unroll
      for (int q = 0; q < 4; ++q) {
        int row = (h * 4 + q) * 16 + l15;
        ca[q] = *reinterpret_cast<const bf16x8*>(reinterpret_cast<const char*>(lds) + row * 1024 + colb);
      }
      __builtin_amdgcn_s_setprio(1);
#pragma unroll
      for (int q = 0; q < 4; ++q)
#pragma unroll
        for (int nt = 0; nt < 4; ++nt)
          acc[h * 4 + q][nt] = __builtin_amdgcn_mfma_f32_16x16x32_bf16(ca[q], cb[nt], acc[h * 4 + q][nt], 0, 0, 0);
      __builtin_amdgcn_s_setprio(0);
    }
#pragma unroll
    for (int q = 0; q < 4; ++q) cb[q] = nb[q];
  }
#pragma unroll
  for (int mt = 0; mt < 8; ++mt)
#pragma unroll
    for (int nt = 0; nt < 4; ++nt) {
      int col = wid * 64 + nt * 16 + l15;
      float bias = b3[col];
      float s = 0.f;
#pragma unroll
      for (int r = 0; r < 4; ++r) s += lrelu(acc[mt][nt][r] + bias);
      s += __shfl_xor(s, 16);
      s += __shfl_xor(s, 32);
      if (lane < 16) {
        // Msum for token t = b*16 + half*8 + mt, k-col 512+col, into XP panel layout
        XP[((b * 32 + 16 + (col >> 5)) << 9) + ((col >> 3) & 3) * 128 + (half * 8 + mt) * 8 + (col & 7)] = f2bf(s);
      }
    }
}

// ---- fusion GEMM + BN partial stats. grid (64,4), 512 thr ----
__global__ __launch_bounds__(512) void k_fusion(const unsigned short* __restrict__ XP,
                                                const unsigned short* __restrict__ WfP,
                                                const float* __restrict__ bfv,
                                                float* __restrict__ y,
                                                float* __restrict__ sums,
                                                float* __restrict__ sumsq) {
  const int tid = threadIdx.x, lane = tid & 63, wid = tid >> 6;
  const int wm = wid >> 2, wn = wid & 3;
  const int l15 = lane & 15;
  const int bx = blockIdx.x, by = blockIdx.y;
  const int rowbase = bx * 64 + wm * 32;
  const int colbase = by * 128 + wn * 32;

  f32x4 acc[2][2];
#pragma unroll
  for (int mt = 0; mt < 2; ++mt)
#pragma unroll
    for (int nt = 0; nt < 2; ++nt) acc[mt][nt] = f32x4{0.f, 0.f, 0.f, 0.f};

  bf16x8 ca[2], cb[2], na[2], nb[2];
  auto ldA = [&](bf16x8 (&d)[2], int ks) {
#pragma unroll
    for (int mt = 0; mt < 2; ++mt)
      d[mt] = *reinterpret_cast<const bf16x8*>(XP + (((bx * 4 + wm * 2 + mt) * 32 + ks) << 9) + lane * 8);
  };
  auto ldB = [&](bf16x8 (&d)[2], int ks) {
#pragma unroll
    for (int nt = 0; nt < 2; ++nt)
      d[nt] = *reinterpret_cast<const bf16x8*>(WfP + (((by * 8 + wn * 2 + nt) * 32 + ks) << 9) + lane * 8);
  };

  ldA(ca, 0); ldB(cb, 0);
  for (int ks = 0; ks < 32; ++ks) {
    int kn = (ks + 1) & 31;
    ldA(na, kn); ldB(nb, kn);
    __builtin_amdgcn_s_setprio(1);
#pragma unroll
    for (int mt = 0; mt < 2; ++mt)
#pragma unroll
      for (int nt = 0; nt < 2; ++nt)
        acc[mt][nt] = __builtin_amdgcn_mfma_f32_16x16x32_bf16(ca[mt], cb[nt], acc[mt][nt], 0, 0, 0);
    __builtin_amdgcn_s_setprio(0);
#pragma unroll
    for (int q = 0; q < 2; ++q) { ca[q] = na[q]; cb[q] = nb[q]; }
  }

  float s[2] = {0.f, 0.f}, q2[2] = {0.f, 0.f};
#pragma unroll
  for (int nt = 0; nt < 2; ++nt) {
    int col = colbase + nt * 16 + l15;
    float bias = bfv[col];
#pragma unroll
    for (int mt = 0; mt < 2; ++mt)
#pragma unroll
      for (int r = 0; r < 4; ++r) {
        int row = rowbase + mt * 16 + (lane >> 4) * 4 + r;
        float v = acc[mt][nt][r] + bias;
        y[row * DD + col] = v;
        s[nt] += v; q2[nt] += v * v;
      }
  }
#pragma unroll
  for (int nt = 0; nt < 2; ++nt) {
    s[nt] += __shfl_xor(s[nt], 16);  s[nt] += __shfl_xor(s[nt], 32);
    q2[nt] += __shfl_xor(q2[nt], 16); q2[nt] += __shfl_xor(q2[nt], 32);
    if (lane < 16) {
      int col = colbase + nt * 16 + l15;
      atomicAdd(&sums[col], s[nt]);
      atomicAdd(&sumsq[col], q2[nt]);
    }
  }
}

// ---- BN apply + lrelu ----
__global__ __launch_bounds__(256) void k_bnapply(const float* __restrict__ y,
                                                 const float* __restrict__ sums,
                                                 const float* __restrict__ sumsq,
                                                 const float* __restrict__ gamma,
                                                 const float* __restrict__ beta,
                                                 float* __restrict__ out) {
  int idx = blockIdx.x * 256 + threadIdx.x;
  if (idx >= NTOK * DD) return;
  int c = idx & 511;
  float mean = sums[c] * (1.0f / 4096.0f);
  float var = sumsq[c] * (1.0f / 4096.0f) - mean * mean;
  float rstd = rsqrtf(var + 1e-5f);
  float v = (y[idx] - mean) * rstd * gamma[c] + beta[c];
  out[idx] = lrelu(v);
}

extern "C" void kernel_launch(void* const* d_in, const int* in_sizes, int n_in,
                              void* d_out, int out_size, void* d_ws, size_t ws_size,
                              hipStream_t stream) {
  const float* F   = (const float*)d_in[0];
  const float* W1  = (const float*)d_in[1];
  const float* b1  = (const float*)d_in[2];
  const float* W2  = (const float*)d_in[3];
  const float* b2  = (const float*)d_in[4];
  const float* W3  = (const float*)d_in[5];
  const float* b3  = (const float*)d_in[6];
  const float* Wf  = (const float*)d_in[7];
  const float* bfv = (const float*)d_in[8];
  const float* gamma = (const float*)d_in[9];
  const float* beta  = (const float*)d_in[10];
  float* out = (float*)d_out;

  char* ws = (char*)d_ws;
  unsigned short* XP  = (unsigned short*)(ws);                              // 8 MB panel [F | Msum]
  unsigned short* ACP = (unsigned short*)(ws + (8u << 20));                 // 8 MB panel
  unsigned short* W1P = (unsigned short*)(ws + (16u << 20));                // 1 MB
  unsigned short* W2P = (unsigned short*)(ws + (17u << 20));                // 0.5 MB
  unsigned short* W3P = (unsigned short*)(ws + (17u << 20) + (512u << 10)); // 0.5 MB
  unsigned short* WfP = (unsigned short*)(ws + (18u << 20));                // 1 MB
  float* y            = (float*)(ws + (19u << 20));                         // 8 MB
  float* sums         = (float*)(ws + (27u << 20));                         // 2 KB
  float* sumsq        = sums + 512;                                         // 2 KB

  k_prep<<<14337, 256, 0, stream>>>(F, W1, W2, W3, Wf, XP, W1P, W2P, W3P, WfP, sums);
  k_gemm_ac<<<dim3(64, 4), 512, 0, stream>>>(XP, W1P, ACP);
  k_relation<<<512, 512, 0, stream>>>(ACP, W2P, W3P, b1, b2, b3, XP);
  k_fusion<<<dim3(64, 4), 512, 0, stream>>>(XP, WfP, bfv, y, sums, sumsq);
  k_bnapply<<<(NTOK * DD + 255) / 256, 256, 0, stream>>>(y, sums, sumsq, gamma, beta, out);
}